// Round 8
// baseline (324.876 us; speedup 1.0000x reference)
//
#include <hip/hip_runtime.h>
#include <hip/hip_bf16.h>
#include <stdint.h>

// MultiHeadAttention fused pipeline for MI355X (gfx950).
// B=4, S=2048, E=768, H=12, D=64.
//  prep_convert: q,k,v fp32 -> bf16 X[8192][768]
//  prep_transpose: W fp32 -> Wt bf16 (Wt[n][k] = W[k][n])
//  qkv_gemm (z): all-bf16 glds GEMM. z<2: C[m=e][n=s] -> Qh plain /
//     Kh d-block XOR-swizzled by s&7 ([BH][S][64], b64 stores). z=2: roles
//     swapped, C[m=s][n=e] -> Vt [BH][64][S] key-block XOR-swizzled by d&7,
//     b64 stores along s (coalesced).
//  attn: double-buffered K/V LDS tiles, ONE barrier per 64-key tile,
//     2x-unrolled body with compile-time buffer indices (loop-invariant LDS
//     addressing), pointer-increment glds prefetch. S^T = K Q^T, fixed-ref
//     softmax via v_exp_f32, mask int4 from global. P^T via per-wave LDS.
//  out_gemm: 64x128 tiles, grid (12,64) for 3 blocks/CU.

typedef __bf16 bf16x8 __attribute__((ext_vector_type(8)));
typedef __bf16 bf16x4 __attribute__((ext_vector_type(4)));
typedef float floatx4 __attribute__((ext_vector_type(4)));

#define MFMA_BF16(a, b, c) __builtin_amdgcn_mfma_f32_16x16x32_bf16(a, b, c, 0, 0, 0)

// MFMA 16x16x32 layouts (verified, learn_hip m89/m91):
//   A frag: A[m = lane&15][k = (lane>>4)*8 + j]
//   B frag: B[k = (lane>>4)*8 + j][n = lane&15]   (read from [n][k] storage)
//   C/D  : C[m = (lane>>4)*4 + r][n = lane&15]
// glds16: 64 lanes x 16 B = 1024 B per instruction, dest = uniform base +
// lane*16B. 128B rows -> 8 rows/chunk (lane>>3, (lane&7)*8); 64B rows ->
// 16 rows/chunk (lane>>2, (lane&3)*8).

__device__ __forceinline__ void glds16(const __bf16* g, __bf16* l) {
  __builtin_amdgcn_global_load_lds(
      (const __attribute__((address_space(1))) unsigned int*)g,
      (__attribute__((address_space(3))) unsigned int*)l, 16, 0, 0);
}

// ---------------------------------------------------------------------------
// prep: fp32 -> bf16 convert of q,k,v. grid (3072, 3), block 256.
// ---------------------------------------------------------------------------
__global__ __launch_bounds__(256) void prep_convert(
    const float* __restrict__ q, const float* __restrict__ k,
    const float* __restrict__ v, __bf16* __restrict__ Xq,
    __bf16* __restrict__ Xk, __bf16* __restrict__ Xv) {
  const int z = blockIdx.y;
  const float* src = (z == 0) ? q : (z == 1) ? k : v;
  __bf16* dst = (z == 0) ? Xq : (z == 1) ? Xk : Xv;
  const size_t i8 = ((size_t)blockIdx.x * 256 + threadIdx.x) * 8;
  float4 f0 = *(const float4*)&src[i8];
  float4 f1 = *(const float4*)&src[i8 + 4];
  bf16x8 o;
  o[0] = (__bf16)f0.x; o[1] = (__bf16)f0.y; o[2] = (__bf16)f0.z; o[3] = (__bf16)f0.w;
  o[4] = (__bf16)f1.x; o[5] = (__bf16)f1.y; o[6] = (__bf16)f1.z; o[7] = (__bf16)f1.w;
  *(bf16x8*)&dst[i8] = o;
}

// ---------------------------------------------------------------------------
// prep: transpose+convert weights. grid (24, 24, 4), block 256.
// ---------------------------------------------------------------------------
__global__ __launch_bounds__(256) void prep_transpose(
    const float* __restrict__ W0, const float* __restrict__ W1,
    const float* __restrict__ W2, const float* __restrict__ W3,
    __bf16* __restrict__ T0, __bf16* __restrict__ T1,
    __bf16* __restrict__ T2, __bf16* __restrict__ T3) {
  const int z = blockIdx.z;
  const float* W = (z == 0) ? W0 : (z == 1) ? W1 : (z == 2) ? W2 : W3;
  __bf16* T = (z == 0) ? T0 : (z == 1) ? T1 : (z == 2) ? T2 : T3;
  __shared__ float t[32][33];
  const int tx = threadIdx.x & 31, ty = threadIdx.x >> 5;
  const int kb = blockIdx.x * 32, nb = blockIdx.y * 32;
#pragma unroll
  for (int j = 0; j < 4; ++j)
    t[ty + j * 8][tx] = W[(size_t)(kb + ty + j * 8) * 768 + nb + tx];
  __syncthreads();
#pragma unroll
  for (int j = 0; j < 4; ++j)
    T[(size_t)(nb + ty + j * 8) * 768 + kb + tx] = (__bf16)t[tx][ty + j * 8];
}

// ---------------------------------------------------------------------------
// QKV projection GEMM. grid (6, 64, 3), block 256. All-bf16, glds16 staging.
// z<2: A=Wt (m=e, bx), B=X (n=s, by).  z=2: A=Xv (m=s, by), B=Wtv (n=e, bx).
// Tile 128x128, BK=32.
// ---------------------------------------------------------------------------
__global__ __launch_bounds__(256) void qkv_gemm(
    const __bf16* __restrict__ Wtq, const __bf16* __restrict__ Wtk,
    const __bf16* __restrict__ Wtv, const __bf16* __restrict__ Xq,
    const __bf16* __restrict__ Xk, const __bf16* __restrict__ Xv,
    const float* __restrict__ bq, const float* __restrict__ bk,
    const float* __restrict__ bv, __bf16* __restrict__ Qh,
    __bf16* __restrict__ Kh, __bf16* __restrict__ Vt) {
  __shared__ __align__(16) __bf16 As[128 * 32];
  __shared__ __align__(16) __bf16 Bs[128 * 32];
  const int z = blockIdx.z;
  const __bf16* Aop = (z == 0) ? Wtq : (z == 1) ? Wtk : Xv;
  const __bf16* Bop = (z == 0) ? Xq : (z == 1) ? Xk : Wtv;
  const int m0 = ((z == 2) ? blockIdx.y : blockIdx.x) * 128;
  const int n0 = ((z == 2) ? blockIdx.x : blockIdx.y) * 128;

  const int tid = threadIdx.x, lane = tid & 63, w = tid >> 6;
  const int quad = lane >> 4, l16 = lane & 15;
  const int wm = (w >> 1) * 64, wn = (w & 1) * 64;

  // staging (64 B rows): wave w insts j=0,1 -> rows w*32 + j*16 + (lane>>2)
  const int grow = w * 32 + (lane >> 2);
  const int gcol = (lane & 3) * 8;
  const __bf16* gA = Aop + (size_t)(m0 + grow) * 768 + gcol;
  const __bf16* gB = Bop + (size_t)(n0 + grow) * 768 + gcol;
  __bf16* lA = As + w * 1024;
  __bf16* lB = Bs + w * 1024;

  floatx4 acc[4][4] = {};

  for (int k0 = 0; k0 < 768; k0 += 32) {
    __syncthreads();
    glds16(gA, lA);
    glds16(gA + (size_t)16 * 768, lA + 512);
    glds16(gB, lB);
    glds16(gB + (size_t)16 * 768, lB + 512);
    gA += 32;
    gB += 32;
    __syncthreads();
    bf16x8 af[4], bfr[4];
#pragma unroll
    for (int t = 0; t < 4; ++t) {
      af[t] = *(const bf16x8*)&As[(wm + t * 16 + l16) * 32 + quad * 8];
      bfr[t] = *(const bf16x8*)&Bs[(wn + t * 16 + l16) * 32 + quad * 8];
    }
#pragma unroll
    for (int mt = 0; mt < 4; ++mt)
#pragma unroll
      for (int nt = 0; nt < 4; ++nt)
        acc[mt][nt] = MFMA_BF16(af[mt], bfr[nt], acc[mt][nt]);
  }

  if (z < 2) {
    const float* bias = (z == 0) ? bq : bk;
    __bf16* Dst = (z == 0) ? Qh : Kh;
#pragma unroll
    for (int mt = 0; mt < 4; ++mt) {
      const int e = m0 + wm + mt * 16 + quad * 4;
      const float4 b4 = *(const float4*)&bias[e];
      const int h = e >> 6, d = e & 63;
#pragma unroll
      for (int nt = 0; nt < 4; ++nt) {
        const int s = n0 + wn + nt * 16 + l16;
        const int bb = s >> 11, sr = s & 2047;
        bf16x4 pv;
        pv[0] = (__bf16)(acc[mt][nt][0] + b4.x);
        pv[1] = (__bf16)(acc[mt][nt][1] + b4.y);
        pv[2] = (__bf16)(acc[mt][nt][2] + b4.z);
        pv[3] = (__bf16)(acc[mt][nt][3] + b4.w);
        // z==1 (K): swizzle d-block by s&7 for conflict-free attn LDS reads
        const int col = (z == 0) ? d : ((((d >> 3) ^ (sr & 7)) << 3) | (d & 7));
        *(bf16x4*)&Dst[((size_t)(bb * 12 + h) * 2048 + sr) * 64 + col] = pv;
      }
    }
  } else {
    // C[m=s][n=e] -> Vt[BH][64 d][2048 s], key-block swizzled by d&7; the
    // 4-reg run lies along s -> contiguous b64 stores at swizzled position.
    float bvn[4];
#pragma unroll
    for (int nt = 0; nt < 4; ++nt) bvn[nt] = bv[n0 + wn + nt * 16 + l16];
#pragma unroll
    for (int mt = 0; mt < 4; ++mt) {
      const int s = m0 + wm + mt * 16 + quad * 4;
      const int bb = s >> 11, sr = s & 2047;
      const int shi = sr & ~63, sblk = (sr >> 3) & 7, soff = sr & 7;
#pragma unroll
      for (int nt = 0; nt < 4; ++nt) {
        const int e = n0 + wn + nt * 16 + l16;
        const int h = e >> 6, d = e & 63;
        bf16x4 pv;
        pv[0] = (__bf16)(acc[mt][nt][0] + bvn[nt]);
        pv[1] = (__bf16)(acc[mt][nt][1] + bvn[nt]);
        pv[2] = (__bf16)(acc[mt][nt][2] + bvn[nt]);
        pv[3] = (__bf16)(acc[mt][nt][3] + bvn[nt]);
        const size_t addr = ((size_t)(bb * 12 + h) * 64 + d) * 2048 + shi +
                            ((sblk ^ (d & 7)) << 3) + soff;
        *(bf16x4*)&Vt[addr] = pv;
      }
    }
  }
}

// ---------------------------------------------------------------------------
// Output projection GEMM. grid (12, 64), block 256. Tile 64(m=e) x 128(n=s),
// 3 blocks/CU. Wave w: 32m x 64n quadrant.
// ---------------------------------------------------------------------------
__global__ __launch_bounds__(256) void out_gemm(const __bf16* __restrict__ Wto,
                                                const __bf16* __restrict__ Ctx,
                                                const float* __restrict__ bo,
                                                float* __restrict__ Out) {
  __shared__ __align__(16) __bf16 As[64 * 32];
  __shared__ __align__(16) __bf16 Bs[128 * 32];
  const int m0 = blockIdx.x * 64, n0 = blockIdx.y * 128;
  const int tid = threadIdx.x, lane = tid & 63, w = tid >> 6;
  const int quad = lane >> 4, l16 = lane & 15;
  const int wm = (w >> 1) * 32, wn = (w & 1) * 64;

  const int gcol = (lane & 3) * 8;
  const __bf16* gA = Wto + (size_t)(m0 + w * 16 + (lane >> 2)) * 768 + gcol;
  const __bf16* gB = Ctx + (size_t)(n0 + w * 32 + (lane >> 2)) * 768 + gcol;
  __bf16* lA = As + w * 512;
  __bf16* lB = Bs + w * 1024;

  floatx4 acc[2][4] = {};
  for (int k0 = 0; k0 < 768; k0 += 32) {
    __syncthreads();
    glds16(gA, lA);
    glds16(gB, lB);
    glds16(gB + (size_t)16 * 768, lB + 512);
    gA += 32;
    gB += 32;
    __syncthreads();
    bf16x8 af[2], bfr[4];
#pragma unroll
    for (int t = 0; t < 2; ++t)
      af[t] = *(const bf16x8*)&As[(wm + t * 16 + l16) * 32 + quad * 8];
#pragma unroll
    for (int t = 0; t < 4; ++t)
      bfr[t] = *(const bf16x8*)&Bs[(wn + t * 16 + l16) * 32 + quad * 8];
#pragma unroll
    for (int mt = 0; mt < 2; ++mt)
#pragma unroll
      for (int nt = 0; nt < 4; ++nt)
        acc[mt][nt] = MFMA_BF16(af[mt], bfr[nt], acc[mt][nt]);
  }

#pragma unroll
  for (int mt = 0; mt < 2; ++mt) {
    const int e = m0 + wm + mt * 16 + quad * 4;
    const float4 b4 = *(const float4*)&bo[e];
#pragma unroll
    for (int nt = 0; nt < 4; ++nt) {
      const int s = n0 + wn + nt * 16 + l16;
      float4 r;
      r.x = acc[mt][nt][0] + b4.x;
      r.y = acc[mt][nt][1] + b4.y;
      r.z = acc[mt][nt][2] + b4.z;
      r.w = acc[mt][nt][3] + b4.w;
      *(float4*)&Out[(size_t)s * 768 + e] = r;
    }
  }
}

// ---------------------------------------------------------------------------
// Flash attention, double-buffered K/V LDS, 1 barrier/tile, 2x-unrolled so
// every LDS address is loop-invariant (ds offsets become immediates).
// grid (16, 48), block 256 (4 waves). Swizzled K/V global layouts make LDS
// frag reads ~conflict-free. S^T = K Q^T; softmax via raw v_exp_f32;
// per-lane sums, one cross-lane reduce at the end; P^T via per-wave LDS.
// ---------------------------------------------------------------------------
__global__ __launch_bounds__(256) void attn_kernel(
    const __bf16* __restrict__ Qh, const __bf16* __restrict__ Kh,
    const __bf16* __restrict__ Vt, const int* __restrict__ mask,
    __bf16* __restrict__ ctx) {
  const int bh = blockIdx.y, b = bh / 12, h = bh - b * 12;
  const int tid = threadIdx.x, lane = tid & 63, w = tid >> 6;
  const int quad = lane >> 4, l16 = lane & 15;
  const int q0 = blockIdx.x * 128 + w * 32;

  __shared__ __align__(16) __bf16 Ks[2][64 * 64];     // [buf][key][d-swz]
  __shared__ __align__(16) __bf16 Vs[2][64 * 64];     // [buf][d][key-swz]
  __shared__ __align__(16) __bf16 Plds[4][32][72];    // [wave][q][key(+pad)]

  const __bf16* Qbase = Qh + (size_t)bh * 2048 * 64;
  const __bf16* Kbase = Kh + (size_t)bh * 2048 * 64;
  const __bf16* Vbase = Vt + (size_t)bh * 64 * 2048;

  // Q B-frags (plain layout): B[k=d][n=q] from Qh[q][d]
  bf16x8 bqf[2][2];
#pragma unroll
  for (int qt = 0; qt < 2; ++qt)
#pragma unroll
    for (int c = 0; c < 2; ++c)
      bqf[qt][c] =
          *(const bf16x8*)&Qbase[(size_t)(q0 + qt * 16 + l16) * 64 + c * 32 + quad * 8];

  // staging: chunk c = w*2+j covers rows c*8 + (lane>>3), col (lane&7)*8.
  const int r0 = w * 16 + (lane >> 3);      // chunk w*2 row
  const int scol = (lane & 7) * 8;
  const int ldsOff = w * 1024;              // chunk w*2 LDS offset (elems)
  const __bf16* pK = Kbase + (size_t)r0 * 64 + scol;      // +512 for chunk w*2+1
  const __bf16* pV = Vbase + (size_t)r0 * 2048 + scol;    // +16384 for chunk w*2+1
  const int* pM = mask + b * 2048 + quad * 4;
  // swizzled fragment column base: block = quad ^ (l16&7)
  const int col0 = (quad ^ (l16 & 7)) * 8;

  // prologue: stage tile 0 into buffer 0
  glds16(pK, &Ks[0][ldsOff]);
  glds16(pK + 512, &Ks[0][ldsOff + 512]);
  glds16(pV, &Vs[0][ldsOff]);
  glds16(pV + 16384, &Vs[0][ldsOff + 512]);
  pK += 4096;
  pV += 64;

  floatx4 o[4][2] = {};  // O^T accs: [d-tile][q-tile]
  float rS[2] = {0.0f, 0.0f};
  const float SC = 0.18033688011112042f;  // 0.125 * log2(e)

  auto body = [&](int cur) {
    const int nxt = cur ^ 1;
    __syncthreads();  // drains this tile's staging (in flight one full body)

    // prefetch next tile (overlaps compute; overruns into adjacent ws
    // buffers on the final tile -- valid memory, never read)
    glds16(pK, &Ks[nxt][ldsOff]);
    glds16(pK + 512, &Ks[nxt][ldsOff + 512]);
    glds16(pV, &Vs[nxt][ldsOff]);
    glds16(pV + 16384, &Vs[nxt][ldsOff + 512]);
    pK += 4096;
    pV += 64;

    int4 mk[4];
#pragma unroll
    for (int t = 0; t < 4; ++t) mk[t] = *(const int4*)(pM + t * 16);
    pM += 64;

    // scores S^T: 4 key-tiles x 2 q-tiles
    floatx4 sc[4][2];
#pragma unroll
    for (int t = 0; t < 4; ++t) {
      bf16x8 ak0 = *(const bf16x8*)&Ks[cur][(t * 16 + l16) * 64 + col0];
      bf16x8 ak1 = *(const bf16x8*)&Ks[cur][(t * 16 + l16) * 64 + (col0 ^ 32)];
#pragma unroll
      for (int qt = 0; qt < 2; ++qt) {
        floatx4 zz = {};
        zz = MFMA_BF16(ak0, bqf[qt][0], zz);
        zz = MFMA_BF16(ak1, bqf[qt][1], zz);
        sc[t][qt] = zz;
      }
    }
    // p = exp2(s*SC + bias); per-lane partial sums
#pragma unroll
    for (int t = 0; t < 4; ++t) {
      const float k0f = mk[t].x ? 0.0f : -1e5f;
      const float k1f = mk[t].y ? 0.0f : -1e5f;
      const float k2f = mk[t].z ? 0.0f : -1e5f;
      const float k3f = mk[t].w ? 0.0f : -1e5f;
#pragma unroll
      for (int qt = 0; qt < 2; ++qt) {
        floatx4 p;
        p[0] = __builtin_amdgcn_exp2f(fmaf(sc[t][qt][0], SC, k0f));
        p[1] = __builtin_amdgcn_exp2f(fmaf(sc[t][qt][1], SC, k1f));
        p[2] = __builtin_amdgcn_exp2f(fmaf(sc[t][qt][2], SC, k2f));
        p[3] = __builtin_amdgcn_exp2f(fmaf(sc[t][qt][3], SC, k3f));
        sc[t][qt] = p;
        rS[qt] += p[0] + p[1] + p[2] + p[3];
      }
    }
    // pack P^T into Plds[q][key] (4 consecutive keys/lane -> b64)
#pragma unroll
    for (int qt = 0; qt < 2; ++qt)
#pragma unroll
      for (int t = 0; t < 4; ++t) {
        bf16x4 pv;
        pv[0] = (__bf16)sc[t][qt][0];
        pv[1] = (__bf16)sc[t][qt][1];
        pv[2] = (__bf16)sc[t][qt][2];
        pv[3] = (__bf16)sc[t][qt][3];
        *(bf16x4*)&Plds[w][qt * 16 + l16][t * 16 + quad * 4] = pv;
      }
    // O^T += V^T @ P^T  (per-wave Plds; in-wave lgkmcnt only)
#pragma unroll
    for (int c = 0; c < 2; ++c) {
      bf16x8 bp[2];
#pragma unroll
      for (int qt = 0; qt < 2; ++qt)
        bp[qt] = *(const bf16x8*)&Plds[w][qt * 16 + l16][c * 32 + quad * 8];
#pragma unroll
      for (int dt = 0; dt < 4; ++dt) {
        bf16x8 av = *(const bf16x8*)&Vs[cur][(dt * 16 + l16) * 64 + (col0 ^ (c * 32))];
#pragma unroll
        for (int qt = 0; qt < 2; ++qt) o[dt][qt] = MFMA_BF16(av, bp[qt], o[dt][qt]);
      }
    }
  };

  for (int it = 0; it < 16; ++it) {
    body(0);
    body(1);
  }

  // cross-lane sum (across quads) + normalize + write ctx
  float inv[2];
#pragma unroll
  for (int qt = 0; qt < 2; ++qt) {
    float s = rS[qt];
    s += __shfl_xor(s, 16, 64);
    s += __shfl_xor(s, 32, 64);
    inv[qt] = 1.0f / s;
  }
#pragma unroll
  for (int dt = 0; dt < 4; ++dt)
#pragma unroll
    for (int qt = 0; qt < 2; ++qt) {
      const int q = q0 + qt * 16 + l16;
      const int d = h * 64 + dt * 16 + quad * 4;
      bf16x4 pv;
      pv[0] = (__bf16)(o[dt][qt][0] * inv[qt]);
      pv[1] = (__bf16)(o[dt][qt][1] * inv[qt]);
      pv[2] = (__bf16)(o[dt][qt][2] * inv[qt]);
      pv[3] = (__bf16)(o[dt][qt][3] * inv[qt]);
      *(bf16x4*)&ctx[(size_t)(b * 2048 + q) * 768 + d] = pv;
    }
}

// ---------------------------------------------------------------------------
extern "C" void kernel_launch(void* const* d_in, const int* in_sizes, int n_in,
                              void* d_out, int out_size, void* d_ws, size_t ws_size,
                              hipStream_t stream) {
  const float* q = (const float*)d_in[0];
  const float* k = (const float*)d_in[1];
  const float* v = (const float*)d_in[2];
  const int* mask = (const int*)d_in[3];
  const float* Wq = (const float*)d_in[4];
  const float* bq = (const float*)d_in[5];
  const float* Wk = (const float*)d_in[6];
  const float* bk = (const float*)d_in[7];
  const float* Wv = (const float*)d_in[8];
  const float* bv = (const float*)d_in[9];
  const float* Wo = (const float*)d_in[10];
  const float* bo = (const float*)d_in[11];
  float* out = (float*)d_out;

  char* ws = (char*)d_ws;
  const size_t SZ = (size_t)8192 * 768 * 2;   // 12.58 MB
  const size_t WSZ = (size_t)768 * 768 * 2;   // 1.18 MB
  __bf16* Xq = (__bf16*)(ws);
  __bf16* Xk = (__bf16*)(ws + SZ);
  __bf16* Xv = (__bf16*)(ws + 2 * SZ);
  __bf16* Qh = (__bf16*)(ws + 3 * SZ);
  __bf16* Kh = (__bf16*)(ws + 4 * SZ);
  __bf16* Vt = (__bf16*)(ws + 5 * SZ);
  __bf16* ctx = (__bf16*)(ws + 6 * SZ);
  __bf16* Wtq = (__bf16*)(ws + 7 * SZ);
  __bf16* Wtk = (__bf16*)(ws + 7 * SZ + WSZ);
  __bf16* Wtv = (__bf16*)(ws + 7 * SZ + 2 * WSZ);
  __bf16* Wto = (__bf16*)(ws + 7 * SZ + 3 * WSZ);

  prep_convert<<<dim3(3072, 3), 256, 0, stream>>>(q, k, v, Xq, Xk, Xv);
  prep_transpose<<<dim3(24, 24, 4), 256, 0, stream>>>(Wq, Wk, Wv, Wo, Wtq, Wtk, Wtv, Wto);
  qkv_gemm<<<dim3(6, 64, 3), 256, 0, stream>>>(Wtq, Wtk, Wtv, Xq, Xk, Xv, bq, bk, bv,
                                               Qh, Kh, Vt);
  attn_kernel<<<dim3(16, 48), 256, 0, stream>>>(Qh, Kh, Vt, mask, ctx);
  out_gemm<<<dim3(12, 64), 256, 0, stream>>>(Wto, ctx, bo, out);
}